// Round 7
// baseline (109.604 us; speedup 1.0000x reference)
//
#include <hip/hip_runtime.h>
#include <hip/hip_bf16.h>
#include <math.h>

#define DM 64
#define NH 4
#define HD 16
#define BATCH 16
#define TSEQ 1024

typedef short bf16x8 __attribute__((ext_vector_type(8)));
typedef short bf16x4 __attribute__((ext_vector_type(4)));
typedef float f32x4  __attribute__((ext_vector_type(4)));
typedef float f32x16 __attribute__((ext_vector_type(16)));
typedef unsigned int u32x4 __attribute__((ext_vector_type(4)));

static __device__ inline short f2bf(float x) {
    __hip_bfloat16 h = __float2bfloat16(x);
    return __builtin_bit_cast(short, h);
}
static __device__ inline float bf2f(short s) {
    __hip_bfloat16 h = __builtin_bit_cast(__hip_bfloat16, s);
    return __bfloat162float(h);
}
// pack two f32 -> one dword of 2 bf16 (RNE), single instruction
static __device__ inline unsigned pkbf(float a, float b) {
    unsigned r;
    asm("v_cvt_pk_bf16_f32 %0, %1, %2" : "=v"(r) : "v"(a), "v"(b));
    return r;
}

// exp2(S) then in-register P -> MFMA A-frag transpose (T12):
// half0 lane holds keys {0-3,8-11,16-19,24-27}, half1 holds {4-7,...}.
// cvt_pk pairs then permlane32_swap: each swap yields two usable A-frag
// dwords. pA0 = keys 0-15, pA1 = keys 16-31.
static __device__ inline void softmax_frags(const f32x16& S, bf16x8& pA0, bf16x8& pA1) {
    float p[16];
    #pragma unroll
    for (int i = 0; i < 16; ++i) p[i] = __builtin_amdgcn_exp2f(S[i]);
    unsigned a0 = pkbf(p[0],  p[1]),  b0 = pkbf(p[4],  p[5]);
    unsigned a1 = pkbf(p[2],  p[3]),  b1 = pkbf(p[6],  p[7]);
    unsigned a2 = pkbf(p[8],  p[9]),  b2 = pkbf(p[12], p[13]);
    unsigned a3 = pkbf(p[10], p[11]), b3 = pkbf(p[14], p[15]);
    asm("v_permlane32_swap_b32 %0, %1" : "+v"(a0), "+v"(b0));
    asm("v_permlane32_swap_b32 %0, %1" : "+v"(a1), "+v"(b1));
    asm("v_permlane32_swap_b32 %0, %1" : "+v"(a2), "+v"(b2));
    asm("v_permlane32_swap_b32 %0, %1" : "+v"(a3), "+v"(b3));
    u32x4 P0v; P0v[0] = a0; P0v[1] = a1; P0v[2] = b0; P0v[3] = b1;
    u32x4 P1v; P1v[0] = a2; P1v[1] = a3; P1v[2] = b2; P1v[3] = b3;
    pA0 = __builtin_bit_cast(bf16x8, P0v);
    pA1 = __builtin_bit_cast(bf16x8, P1v);
}

// ---------------- Kernel 1: MFMA Q/K/V projections -> bf16 ----------------
// REWRITE (attn untouched): proj as MFMA GEMM so every input row is read
// exactly ONCE (R5 read x 4x / enc 8x; traffic 60 -> ~26 MB).
// grid = 256 blocks x 256 thr (4 waves). Blocks 0-127: x -> q (2 col-tiles,
// qscale folded into staged Wq + bias). Blocks 128-255: enc -> k (tiles 0-1)
// + v (tiles 2-3, mask folded, ones-row d=16 = mask).
// Per wave: 32 rows; A-frags (hi/lo bf16) from global; B-frags (hi/lo)
// staged in LDS (same pattern as attn's Wl); 3-term mfma_32x32x16_bf16
// per K-chunk ~ f32 precision. D: col=l31, row=(r&3)+8*(r>>2)+4*half.
__global__ __launch_bounds__(256) void proj_kernel(
    const float* __restrict__ x, const float* __restrict__ enc,
    const float* __restrict__ Wkv, const float* __restrict__ bkv,
    const float* __restrict__ Wq,  const float* __restrict__ bq,
    const int* __restrict__ mask,
    short* __restrict__ qhi, short* __restrict__ qlo,
    short* __restrict__ khi, short* __restrict__ klo,
    short* __restrict__ vtt)
{
    const int tid  = threadIdx.x;
    const int lane = tid & 63;
    const int wid  = tid >> 6;            // 0..3
    const int l31 = lane & 31, half = lane >> 5;

    const int bi = blockIdx.x;            // 0..255
    const bool isq = (bi < 128);
    const int rowbase = (isq ? bi : bi - 128) * 128;   // 128 rows/block, one batch
    const float* in  = isq ? x : enc;
    const int nt  = isq ? 2 : 4;
    const int ldw = isq ? 64 : 128;
    const float* W = isq ? Wq : Wkv;
    const float qscale = 0.36067376022224085f;  // 0.25 * log2(e)

    __shared__ u32x4 Bw[4][4][2][64];     // [tile][chunk][hi/lo][lane] B-frags
    __shared__ float smask[128];          // enc blocks only

    // ---- stage weight B-frags (hi/lo); fold qscale for q ----
    for (int s = tid; s < nt*512; s += 256) {
        const int lane6 = s & 63;
        const int hl   = (s >> 6) & 1;
        const int ch   = (s >> 7) & 3;
        const int tile = s >> 9;
        const int col  = tile*32 + (lane6 & 31);
        const int kr   = ch*16 + (lane6 >> 5)*8;
        u32x4 wv;
        #pragma unroll
        for (int jj = 0; jj < 4; ++jj) {
            float w0 = W[(kr + 2*jj)*ldw + col];
            float w1 = W[(kr + 2*jj + 1)*ldw + col];
            if (isq) { w0 *= qscale; w1 *= qscale; }
            const unsigned hw = pkbf(w0, w1);
            if (hl == 0) wv[jj] = hw;
            else         wv[jj] = pkbf(w0 - bf2f((short)(hw & 0xffff)),
                                       w1 - bf2f((short)(hw >> 16)));
        }
        Bw[tile][ch][hl][lane6] = wv;
    }
    if (!isq && tid < 128) {
        const int bb = rowbase >> 10, tb = rowbase & 1023;
        smask[tid] = (mask[bb*TSEQ + tb + tid] != 0) ? 1.0f : 0.0f;
    }

    // ---- A-frags for this wave's 32 rows: A[m=l31][k=half*8+j], 4 K-chunks,
    // hi/lo; input row read exactly once (issued before the barrier) ----
    const int rw = rowbase + wid*32;
    const int b = rw >> 10, trow = rw & 1023;       // trow multiple of 32
    const float* arow = in + (size_t)(rw + l31)*64 + half*8;
    bf16x8 Ah[4], Al[4];
    #pragma unroll
    for (int c = 0; c < 4; ++c) {
        const float4 f0 = *(const float4*)(arow + c*16);
        const float4 f1 = *(const float4*)(arow + c*16 + 4);
        const float v[8] = {f0.x,f0.y,f0.z,f0.w, f1.x,f1.y,f1.z,f1.w};
        u32x4 hv, lv;
        #pragma unroll
        for (int jj = 0; jj < 4; ++jj) {
            const unsigned hw = pkbf(v[2*jj], v[2*jj+1]);
            hv[jj] = hw;
            lv[jj] = pkbf(v[2*jj]   - bf2f((short)(hw & 0xffff)),
                          v[2*jj+1] - bf2f((short)(hw >> 16)));
        }
        Ah[c] = __builtin_bit_cast(bf16x8, hv);
        Al[c] = __builtin_bit_cast(bf16x8, lv);
    }
    __syncthreads();

    // ---- per col-tile: D = A @ Bw[tile] + bias; write out ----
    for (int tile = 0; tile < nt; ++tile) {
        const int col = tile*32 + l31;
        const float bv = isq ? bq[col]*qscale : bkv[col];
        f32x16 D;
        #pragma unroll
        for (int i = 0; i < 16; ++i) D[i] = bv;
        #pragma unroll
        for (int c = 0; c < 4; ++c) {
            const bf16x8 Bh = __builtin_bit_cast(bf16x8, Bw[tile][c][0][lane]);
            const bf16x8 Bl = __builtin_bit_cast(bf16x8, Bw[tile][c][1][lane]);
            D = __builtin_amdgcn_mfma_f32_32x32x16_bf16(Ah[c], Bh, D, 0, 0, 0);
            D = __builtin_amdgcn_mfma_f32_32x32x16_bf16(Ah[c], Bl, D, 0, 0, 0);
            D = __builtin_amdgcn_mfma_f32_32x32x16_bf16(Al[c], Bh, D, 0, 0, 0);
        }

        if (isq || tile < 2) {
            // q or k: hi/lo split, scalar 2-B stores (rows in-lane)
            short* dh = isq ? qhi : khi;
            short* dl = isq ? qlo : klo;
            const int head = col >> 4;       // 0..3
            const int d    = col & 15;
            const size_t base = (((size_t)(b*NH + head))*TSEQ + trow)*HD + d;
            #pragma unroll
            for (int r = 0; r < 16; ++r) {
                const int m = (r & 3) + 8*(r >> 2) + 4*half;
                const float vf = D[r];
                const short hb = f2bf(vf);
                dh[base + (size_t)m*HD] = hb;
                dl[base + (size_t)m*HD] = f2bf(vf - bf2f(hb));
            }
        } else {
            // v tiles: cols 64..127 -> vtt[b][h][kb][d][kw], mask folded
            const int vcol = col - 64;
            const int head = vcol >> 4, d = vcol & 15;
            short* tp = vtt + ((size_t)(b*NH + head))*32768 + (size_t)(trow >> 5)*1024;
            unsigned* tp32 = (unsigned*)tp;
            #pragma unroll
            for (int r = 0; r < 16; r += 2) {
                const int m = (r & 3) + 8*(r >> 2) + 4*half;   // even, pair m,m+1
                const float mb0 = smask[wid*32 + m];
                const float mb1 = smask[wid*32 + m + 1];
                tp32[(d*32 + m) >> 1] = pkbf(D[r]*mb0, D[r+1]*mb1);
            }
            if (d == 0) {  // ones/mask row (d=16) for this head
                #pragma unroll
                for (int r = 0; r < 16; r += 2) {
                    const int m = (r & 3) + 8*(r >> 2) + 4*half;
                    const unsigned o0 = (smask[wid*32+m]   != 0.f) ? 0x3F80u : 0u;
                    const unsigned o1 = (smask[wid*32+m+1] != 0.f) ? 0x3F80u : 0u;
                    tp32[(16*32 + m) >> 1] = o0 | (o1 << 16);
                }
            }
        }
    }
}

// ---------------- Kernel 2: MFMA flash attention + MFMA Wproj epilogue -----
// (UNCHANGED from the passing R5 version.)
// grid = 256 blocks 1-D with XCD-affinity decode (XCD x -> batches {x,x+8}).
// Each block: 64 q-rows (2 subtiles of 32) x 8 waves (4 heads x 2 key
// halves). K/V frags loaded once per step feed BOTH q-subtiles.
__global__ __launch_bounds__(512) void attn_kernel(
    const short* __restrict__ qhi, const short* __restrict__ qlo,
    const short* __restrict__ khi, const short* __restrict__ klo,
    const short* __restrict__ vtt,
    const float* __restrict__ Wproj, const float* __restrict__ bproj,
    float* __restrict__ out)
{
    const int tid  = threadIdx.x;
    const int lane = tid & 63;
    const int wid  = __builtin_amdgcn_readfirstlane(tid >> 6);  // 0..7
    const int h  = wid & 3;
    const int ks = wid >> 2;          // key half
    const int l31 = lane & 31, half = lane >> 5;

    // XCD-affinity decode (round-robin block->XCD)
    const int bi  = blockIdx.x;            // 0..255
    const int xcd = bi & 7, u = bi >> 3;   // u: 0..31
    const int b     = xcd + ((u >> 4) << 3);   // batches {x, x+8} on XCD x
    const int qbase = (u & 15) * 64;

    __shared__ float Cbuf[2][64][68];    // [ks][qrow][col]; 16B-aligned rows
    __shared__ float Lbuf[2][NH][64];
    __shared__ u32x4 Wl[2][4][2][64];    // [ct][kstep][hi/lo][lane] B-frags of Wproj

    // ---- stage Wproj as bf16 hi/lo MFMA B-frags (16 KB, once per block) ----
    #pragma unroll
    for (int it = 0; it < 2; ++it) {
        const int s = tid + it*512;          // slot 0..1023
        const int lane6 = s & 63;
        const int hl  = (s >> 6) & 1;
        const int stp = (s >> 7) & 3;
        const int ctc = s >> 9;
        const int c  = ctc*32 + (lane6 & 31);
        const int kb = stp*16 + (lane6 >> 5)*8;
        u32x4 wv;
        #pragma unroll
        for (int jj = 0; jj < 4; ++jj) {
            const float w0 = Wproj[(kb + 2*jj)*DM + c];
            const float w1 = Wproj[(kb + 2*jj + 1)*DM + c];
            if (hl == 0) {
                wv[jj] = pkbf(w0, w1);
            } else {
                const float h0 = bf2f(f2bf(w0));
                const float h1 = bf2f(f2bf(w1));
                wv[jj] = pkbf(w0 - h0, w1 - h1);
            }
        }
        Wl[ctc][stp][hl][lane6] = wv;
    }
    __syncthreads();

    // Q frags for both subtiles (MFMA B-operand: B[k=half*8+j][n=qrow=l31])
    const size_t qoff = (((size_t)(b*NH + h))*TSEQ + qbase + l31)*HD + half*8;
    const bf16x8 qAh0 = *(const bf16x8*)(qhi + qoff);
    const bf16x8 qAl0 = *(const bf16x8*)(qlo + qoff);
    const bf16x8 qAh1 = *(const bf16x8*)(qhi + qoff + 32*HD);
    const bf16x8 qAl1 = *(const bf16x8*)(qlo + qoff + 32*HD);

    const short* khb = khi + (((size_t)(b*NH + h))*TSEQ + ks*512)*HD;
    const short* klb = klo + (((size_t)(b*NH + h))*TSEQ + ks*512)*HD;
    const short* vtb = vtt + ((size_t)(b*NH + h))*32768 + (size_t)ks*16384;

    f32x16 Cacc0, Cacc1;
    #pragma unroll
    for (int i = 0; i < 16; ++i) { Cacc0[i] = 0.f; Cacc1[i] = 0.f; }

    for (int step = 0; step < 16; ++step) {
        const int ko = step * 32;
        // K frags (MFMA A-operand: A[m=key=l31][k=half*8+j])
        const bf16x8 kBh = *(const bf16x8*)(khb + (size_t)(ko + l31)*HD + half*8);
        const bf16x8 kBl = *(const bf16x8*)(klb + (size_t)(ko + l31)*HD + half*8);
        // V B-frags from tiled vtt: B[k=kw][n=d=l31]; lane stride 64 B
        const short* tile = vtb + (size_t)step * 1024;
        const bf16x8 vB0 = *(const bf16x8*)(tile + l31*32 + half*8);        // keys 0-15
        const bf16x8 vB1 = *(const bf16x8*)(tile + l31*32 + 16 + half*8);   // keys 16-31

        // ---- subtile 0 ----
        {
            f32x16 S;
            #pragma unroll
            for (int i = 0; i < 16; ++i) S[i] = 0.f;
            S = __builtin_amdgcn_mfma_f32_32x32x16_bf16(kBh, qAh0, S, 0, 0, 0);
            S = __builtin_amdgcn_mfma_f32_32x32x16_bf16(kBl, qAh0, S, 0, 0, 0);
            S = __builtin_amdgcn_mfma_f32_32x32x16_bf16(kBh, qAl0, S, 0, 0, 0);
            bf16x8 pA0, pA1;
            softmax_frags(S, pA0, pA1);
            Cacc0 = __builtin_amdgcn_mfma_f32_32x32x16_bf16(pA0, vB0, Cacc0, 0, 0, 0);
            Cacc0 = __builtin_amdgcn_mfma_f32_32x32x16_bf16(pA1, vB1, Cacc0, 0, 0, 0);
        }
        // ---- subtile 1 ----
        {
            f32x16 S;
            #pragma unroll
            for (int i = 0; i < 16; ++i) S[i] = 0.f;
            S = __builtin_amdgcn_mfma_f32_32x32x16_bf16(kBh, qAh1, S, 0, 0, 0);
            S = __builtin_amdgcn_mfma_f32_32x32x16_bf16(kBl, qAh1, S, 0, 0, 0);
            S = __builtin_amdgcn_mfma_f32_32x32x16_bf16(kBh, qAl1, S, 0, 0, 0);
            bf16x8 pA0, pA1;
            softmax_frags(S, pA0, pA1);
            Cacc1 = __builtin_amdgcn_mfma_f32_32x32x16_bf16(pA0, vB0, Cacc1, 0, 0, 0);
            Cacc1 = __builtin_amdgcn_mfma_f32_32x32x16_bf16(pA1, vB1, Cacc1, 0, 0, 0);
        }
    }

    // publish partials: D[m=qrow][n=d]; cols 0-15 = ctx(d), col 16 = l
    #pragma unroll
    for (int r = 0; r < 16; ++r) {
        const int row = (r & 3) + 8*(r >> 2) + 4*half;
        if (l31 < 16) {
            Cbuf[ks][row][h*HD + l31]      = Cacc0[r];
            Cbuf[ks][32 + row][h*HD + l31] = Cacc1[r];
        } else if (l31 == 16) {
            Lbuf[ks][h][row]      = Cacc0[r];
            Lbuf[ks][h][32 + row] = Cacc1[r];
        }
    }
    __syncthreads();

    // ---- MFMA epilogue: out[64 x 64] = (ctx * linv) @ Wproj + bproj ----
    // 4 waves: ct = wid&1 (col tile), rt = wid>>1 (row tile)
    if (wid < 4) {
        const int ct = wid & 1, rt = wid >> 1;
        const int t  = rt*32 + l31;          // qrow (A m-index)
        const int c  = ct*32 + l31;          // out col (B/D n-index)
        f32x16 D;
        const float bp = bproj[c];
        #pragma unroll
        for (int i = 0; i < 16; ++i) D[i] = bp;

        #pragma unroll
        for (int stp = 0; stp < 4; ++stp) {
            const float linv = 1.0f / (Lbuf[0][stp][t] + Lbuf[1][stp][t]);
            const int ib = stp*16 + half*8;
            const float4 x0 = *(const float4*)&Cbuf[0][t][ib];
            const float4 x1 = *(const float4*)&Cbuf[0][t][ib+4];
            const float4 y0 = *(const float4*)&Cbuf[1][t][ib];
            const float4 y1 = *(const float4*)&Cbuf[1][t][ib+4];
            float cv[8];
            cv[0] = (x0.x+y0.x)*linv; cv[1] = (x0.y+y0.y)*linv;
            cv[2] = (x0.z+y0.z)*linv; cv[3] = (x0.w+y0.w)*linv;
            cv[4] = (x1.x+y1.x)*linv; cv[5] = (x1.y+y1.y)*linv;
            cv[6] = (x1.z+y1.z)*linv; cv[7] = (x1.w+y1.w)*linv;
            u32x4 Ahv, Alv;
            #pragma unroll
            for (int jj = 0; jj < 4; ++jj) {
                const unsigned hw = pkbf(cv[2*jj], cv[2*jj+1]);
                const float h0 = bf2f((short)(hw & 0xffff));
                const float h1 = bf2f((short)(hw >> 16));
                Ahv[jj] = hw;
                Alv[jj] = pkbf(cv[2*jj] - h0, cv[2*jj+1] - h1);
            }
            const bf16x8 Ah = __builtin_bit_cast(bf16x8, Ahv);
            const bf16x8 Al = __builtin_bit_cast(bf16x8, Alv);
            const bf16x8 Bh = __builtin_bit_cast(bf16x8, Wl[ct][stp][0][lane]);
            const bf16x8 Bl = __builtin_bit_cast(bf16x8, Wl[ct][stp][1][lane]);
            D = __builtin_amdgcn_mfma_f32_32x32x16_bf16(Ah, Bh, D, 0, 0, 0);
            D = __builtin_amdgcn_mfma_f32_32x32x16_bf16(Ah, Bl, D, 0, 0, 0);
            D = __builtin_amdgcn_mfma_f32_32x32x16_bf16(Al, Bh, D, 0, 0, 0);
        }
        float* orow = out + ((size_t)b*TSEQ + qbase + rt*32)*DM + c;
        #pragma unroll
        for (int r = 0; r < 16; ++r) {
            const int tr = (r & 3) + 8*(r >> 2) + 4*half;
            orow[(size_t)tr * DM] = D[r];
        }
    }
}

extern "C" void kernel_launch(void* const* d_in, const int* in_sizes, int n_in,
                              void* d_out, int out_size, void* d_ws, size_t ws_size,
                              hipStream_t stream) {
    const float* x     = (const float*)d_in[0];
    const float* enc   = (const float*)d_in[1];
    const int*   mask  = (const int*)  d_in[2];
    const float* Wkv   = (const float*)d_in[3];
    const float* bkv   = (const float*)d_in[4];
    const float* Wq    = (const float*)d_in[5];
    const float* bq    = (const float*)d_in[6];
    const float* Wproj = (const float*)d_in[7];
    const float* bproj = (const float*)d_in[8];
    float* out = (float*)d_out;

    // ws: qhi,qlo,khi,klo 2MB each + vtt tiled (32 d-rows) 4MB = 12MB
    const size_t SZ = (size_t)BATCH*NH*TSEQ*HD;
    short* qhi = (short*)d_ws;
    short* qlo = qhi + SZ;
    short* khi = qlo + SZ;
    short* klo = khi + SZ;
    short* vtt = klo + SZ;   // BATCH*NH*32768 shorts

    proj_kernel<<<dim3(256), dim3(256), 0, stream>>>(
        x, enc, Wkv, bkv, Wq, bq, mask, qhi, qlo, khi, klo, vtt);
    attn_kernel<<<dim3(256), dim3(512), 0, stream>>>(
        qhi, qlo, khi, klo, vtt, Wproj, bproj, out);
}

// Round 8
// 105.316 us; speedup vs baseline: 1.0407x; 1.0407x over previous
//
#include <hip/hip_runtime.h>
#include <hip/hip_bf16.h>
#include <math.h>

#define DM 64
#define NH 4
#define HD 16
#define BATCH 16
#define TSEQ 1024

typedef short bf16x8 __attribute__((ext_vector_type(8)));
typedef short bf16x4 __attribute__((ext_vector_type(4)));
typedef float f32x4  __attribute__((ext_vector_type(4)));
typedef float f32x16 __attribute__((ext_vector_type(16)));
typedef unsigned int u32x4 __attribute__((ext_vector_type(4)));

static __device__ inline short f2bf(float x) {
    __hip_bfloat16 h = __float2bfloat16(x);
    return __builtin_bit_cast(short, h);
}
static __device__ inline float bf2f(short s) {
    __hip_bfloat16 h = __builtin_bit_cast(__hip_bfloat16, s);
    return __bfloat162float(h);
}
// pack two f32 -> one dword of 2 bf16 (RNE), single instruction
static __device__ inline unsigned pkbf(float a, float b) {
    unsigned r;
    asm("v_cvt_pk_bf16_f32 %0, %1, %2" : "=v"(r) : "v"(a), "v"(b));
    return r;
}

// exp2(S) then in-register P -> MFMA A-frag transpose (T12):
// half0 lane holds keys {0-3,8-11,16-19,24-27}, half1 holds {4-7,...}.
// cvt_pk pairs then permlane32_swap: each swap yields two usable A-frag
// dwords. pA0 = keys 0-15, pA1 = keys 16-31.
static __device__ inline void softmax_frags(const f32x16& S, bf16x8& pA0, bf16x8& pA1) {
    float p[16];
    #pragma unroll
    for (int i = 0; i < 16; ++i) p[i] = __builtin_amdgcn_exp2f(S[i]);
    unsigned a0 = pkbf(p[0],  p[1]),  b0 = pkbf(p[4],  p[5]);
    unsigned a1 = pkbf(p[2],  p[3]),  b1 = pkbf(p[6],  p[7]);
    unsigned a2 = pkbf(p[8],  p[9]),  b2 = pkbf(p[12], p[13]);
    unsigned a3 = pkbf(p[10], p[11]), b3 = pkbf(p[14], p[15]);
    asm("v_permlane32_swap_b32 %0, %1" : "+v"(a0), "+v"(b0));
    asm("v_permlane32_swap_b32 %0, %1" : "+v"(a1), "+v"(b1));
    asm("v_permlane32_swap_b32 %0, %1" : "+v"(a2), "+v"(b2));
    asm("v_permlane32_swap_b32 %0, %1" : "+v"(a3), "+v"(b3));
    u32x4 P0v; P0v[0] = a0; P0v[1] = a1; P0v[2] = b0; P0v[3] = b1;
    u32x4 P1v; P1v[0] = a2; P1v[1] = a3; P1v[2] = b2; P1v[3] = b3;
    pA0 = __builtin_bit_cast(bf16x8, P0v);
    pA1 = __builtin_bit_cast(bf16x8, P1v);
}

// ---------------- Kernel 1: fused Q/K/V projections -> bf16 ---------------
// (REVERTED to the proven R5 version: R6 wide-part and R7 MFMA rewrites both
// regressed — proj is not read-traffic-bound; inputs are L3-resident.)
// grid = (64 rowblocks, 12 parts), 256 thr, thread = 1 row x 16 cols (one
// full head). parts 0-3: q (scaled 0.25*log2e, hi/lo), 4-7: k (hi/lo),
// 8-11: v -> TILED vtt[b][h][kb][d][kw] with mask folded in (v *= mask,
// ones-row d=16 = mask). x read 4x, enc 8x.
__global__ __launch_bounds__(256) void proj_kernel(
    const float* __restrict__ x, const float* __restrict__ enc,
    const float* __restrict__ Wkv, const float* __restrict__ bkv,
    const float* __restrict__ Wq,  const float* __restrict__ bq,
    const int* __restrict__ mask,
    short* __restrict__ qhi, short* __restrict__ qlo,
    short* __restrict__ khi, short* __restrict__ klo,
    short* __restrict__ vtt)
{
    const int t = threadIdx.x;
    const int part = blockIdx.y;          // 0..11
    const int r = blockIdx.x * 256 + t;   // global row 0..16383
    const int b = r >> 10, trow = r & 1023;

    const float* in; const float* W; const float* bias; int cb, ldw;
    if (part < 4)      { in = x;   W = Wq;  ldw = 64;  cb = part*16;          bias = bq;  }
    else if (part < 8) { in = enc; W = Wkv; ldw = 128; cb = (part-4)*16;      bias = bkv; }
    else               { in = enc; W = Wkv; ldw = 128; cb = 64 + (part-8)*16; bias = bkv; }

    __shared__ float wsl[64][16];
    for (int idx = t; idx < 1024; idx += 256)
        wsl[idx >> 4][idx & 15] = W[(idx >> 4)*ldw + cb + (idx & 15)];

    // full input row up front (latency overlaps the staging barrier)
    float4 xr[16];
    const float4* inrow = (const float4*)(in + (size_t)r * 64);
    #pragma unroll
    for (int i = 0; i < 16; ++i) xr[i] = inrow[i];
    __syncthreads();

    float acc[16];
    #pragma unroll
    for (int j = 0; j < 16; ++j) acc[j] = bias[cb + j];
    #pragma unroll
    for (int k = 0; k < 64; ++k) {
        const float xv = ((const float*)xr)[k];
        const float4 w0 = ((const float4*)&wsl[k][0])[0];
        const float4 w1 = ((const float4*)&wsl[k][0])[1];
        const float4 w2 = ((const float4*)&wsl[k][0])[2];
        const float4 w3 = ((const float4*)&wsl[k][0])[3];
        acc[0]  += xv*w0.x; acc[1]  += xv*w0.y; acc[2]  += xv*w0.z; acc[3]  += xv*w0.w;
        acc[4]  += xv*w1.x; acc[5]  += xv*w1.y; acc[6]  += xv*w1.z; acc[7]  += xv*w1.w;
        acc[8]  += xv*w2.x; acc[9]  += xv*w2.y; acc[10] += xv*w2.z; acc[11] += xv*w2.w;
        acc[12] += xv*w3.x; acc[13] += xv*w3.y; acc[14] += xv*w3.z; acc[15] += xv*w3.w;
    }

    if (part < 8) {
        // q: fold softmax scale AND log2(e) so attn uses exp2 directly
        const float scale = (part < 4) ? 0.36067376022224085f : 1.0f;
        short* dh = (part < 4) ? qhi : khi;
        short* dl = (part < 4) ? qlo : klo;
        const int h = (part < 4) ? part : (part - 4);
        bf16x8 h0, h1, l0, l1;
        #pragma unroll
        for (int j = 0; j < 16; ++j) {
            float vf = acc[j] * scale;
            short hb = f2bf(vf);
            short lb = f2bf(vf - bf2f(hb));
            if (j < 8) { h0[j] = hb; l0[j] = lb; }
            else       { h1[j-8] = hb; l1[j-8] = lb; }
        }
        size_t off = (((size_t)(b*NH + h))*TSEQ + trow)*HD;
        *(bf16x8*)(dh + off)     = h0;
        *(bf16x8*)(dh + off + 8) = h1;
        *(bf16x8*)(dl + off)     = l0;
        *(bf16x8*)(dl + off + 8) = l1;
    } else {
        // vtt[b][h][kb=key>>5][d(32: 0-15 data, 16 maskbit, 17-31 unused)][kw=key&31]
        const int h = part - 8;
        const float mb = (mask[b*TSEQ + trow] != 0) ? 1.0f : 0.0f;
        short* tile = vtt + ((size_t)(b*NH + h))*32768 + (size_t)(trow >> 5)*1024;
        const int kw = trow & 31;
        #pragma unroll
        for (int j = 0; j < 16; ++j)
            tile[j*32 + kw] = f2bf(acc[j] * mb);
        tile[16*32 + kw] = (mb != 0.0f) ? (short)0x3F80 : (short)0;  // ones/mask row
    }
}

// ---------------- Kernel 2: MFMA flash attention + MFMA Wproj epilogue -----
// grid = 256 blocks 1-D with XCD-affinity decode (XCD x -> batches {x,x+8}).
// Each block: 64 q-rows (2 subtiles of 32) x 8 waves (4 heads x 2 key
// halves). K/V frags loaded once per step feed BOTH q-subtiles.
// SINGLE change vs passing R5: s_setprio(1) around each MFMA cluster (T5).
// The K-loop has no barriers, so the block's 8 waves run mutually async in
// different phases -> the CU scheduler can favor MFMA-issuing waves
// (guide m191: +4-7% attn in exactly this independent-wave regime).
// Pure scheduler hint: zero correctness risk.
// Per 32-key step, per subtile:
//   S^T = 3x mfma_32x32x16_bf16 swapped (A=K, B=Q) -> lane-local P-row
//   softmax_frags: exp2 + cvt_pk + permlane32_swap (in-register transpose)
//   ctx += 2x mfma (A=P, B=tiled vtt; col 16 of vtt = maskbit -> l for free)
// Epilogue: ctx @ Wproj via MFMA, Wproj staged once per block in LDS as
// bf16 hi/lo B-frags; 4 waves each do one 32x32 out tile.
__global__ __launch_bounds__(512) void attn_kernel(
    const short* __restrict__ qhi, const short* __restrict__ qlo,
    const short* __restrict__ khi, const short* __restrict__ klo,
    const short* __restrict__ vtt,
    const float* __restrict__ Wproj, const float* __restrict__ bproj,
    float* __restrict__ out)
{
    const int tid  = threadIdx.x;
    const int lane = tid & 63;
    const int wid  = __builtin_amdgcn_readfirstlane(tid >> 6);  // 0..7
    const int h  = wid & 3;
    const int ks = wid >> 2;          // key half
    const int l31 = lane & 31, half = lane >> 5;

    // XCD-affinity decode (round-robin block->XCD)
    const int bi  = blockIdx.x;            // 0..255
    const int xcd = bi & 7, u = bi >> 3;   // u: 0..31
    const int b     = xcd + ((u >> 4) << 3);   // batches {x, x+8} on XCD x
    const int qbase = (u & 15) * 64;

    __shared__ float Cbuf[2][64][68];    // [ks][qrow][col]; 16B-aligned rows
    __shared__ float Lbuf[2][NH][64];
    __shared__ u32x4 Wl[2][4][2][64];    // [ct][kstep][hi/lo][lane] B-frags of Wproj

    // ---- stage Wproj as bf16 hi/lo MFMA B-frags (16 KB, once per block) ----
    #pragma unroll
    for (int it = 0; it < 2; ++it) {
        const int s = tid + it*512;          // slot 0..1023
        const int lane6 = s & 63;
        const int hl  = (s >> 6) & 1;
        const int stp = (s >> 7) & 3;
        const int ctc = s >> 9;
        const int c  = ctc*32 + (lane6 & 31);
        const int kb = stp*16 + (lane6 >> 5)*8;
        u32x4 wv;
        #pragma unroll
        for (int jj = 0; jj < 4; ++jj) {
            const float w0 = Wproj[(kb + 2*jj)*DM + c];
            const float w1 = Wproj[(kb + 2*jj + 1)*DM + c];
            if (hl == 0) {
                wv[jj] = pkbf(w0, w1);
            } else {
                const float h0 = bf2f(f2bf(w0));
                const float h1 = bf2f(f2bf(w1));
                wv[jj] = pkbf(w0 - h0, w1 - h1);
            }
        }
        Wl[ctc][stp][hl][lane6] = wv;
    }
    __syncthreads();

    // Q frags for both subtiles (MFMA B-operand: B[k=half*8+j][n=qrow=l31])
    const size_t qoff = (((size_t)(b*NH + h))*TSEQ + qbase + l31)*HD + half*8;
    const bf16x8 qAh0 = *(const bf16x8*)(qhi + qoff);
    const bf16x8 qAl0 = *(const bf16x8*)(qlo + qoff);
    const bf16x8 qAh1 = *(const bf16x8*)(qhi + qoff + 32*HD);
    const bf16x8 qAl1 = *(const bf16x8*)(qlo + qoff + 32*HD);

    const short* khb = khi + (((size_t)(b*NH + h))*TSEQ + ks*512)*HD;
    const short* klb = klo + (((size_t)(b*NH + h))*TSEQ + ks*512)*HD;
    const short* vtb = vtt + ((size_t)(b*NH + h))*32768 + (size_t)ks*16384;

    f32x16 Cacc0, Cacc1;
    #pragma unroll
    for (int i = 0; i < 16; ++i) { Cacc0[i] = 0.f; Cacc1[i] = 0.f; }

    for (int step = 0; step < 16; ++step) {
        const int ko = step * 32;
        // K frags (MFMA A-operand: A[m=key=l31][k=half*8+j])
        const bf16x8 kBh = *(const bf16x8*)(khb + (size_t)(ko + l31)*HD + half*8);
        const bf16x8 kBl = *(const bf16x8*)(klb + (size_t)(ko + l31)*HD + half*8);
        // V B-frags from tiled vtt: B[k=kw][n=d=l31]; lane stride 64 B
        const short* tile = vtb + (size_t)step * 1024;
        const bf16x8 vB0 = *(const bf16x8*)(tile + l31*32 + half*8);        // keys 0-15
        const bf16x8 vB1 = *(const bf16x8*)(tile + l31*32 + 16 + half*8);   // keys 16-31

        // ---- subtile 0 ----
        {
            f32x16 S;
            #pragma unroll
            for (int i = 0; i < 16; ++i) S[i] = 0.f;
            __builtin_amdgcn_s_setprio(1);
            S = __builtin_amdgcn_mfma_f32_32x32x16_bf16(kBh, qAh0, S, 0, 0, 0);
            S = __builtin_amdgcn_mfma_f32_32x32x16_bf16(kBl, qAh0, S, 0, 0, 0);
            S = __builtin_amdgcn_mfma_f32_32x32x16_bf16(kBh, qAl0, S, 0, 0, 0);
            __builtin_amdgcn_s_setprio(0);
            bf16x8 pA0, pA1;
            softmax_frags(S, pA0, pA1);
            __builtin_amdgcn_s_setprio(1);
            Cacc0 = __builtin_amdgcn_mfma_f32_32x32x16_bf16(pA0, vB0, Cacc0, 0, 0, 0);
            Cacc0 = __builtin_amdgcn_mfma_f32_32x32x16_bf16(pA1, vB1, Cacc0, 0, 0, 0);
            __builtin_amdgcn_s_setprio(0);
        }
        // ---- subtile 1 ----
        {
            f32x16 S;
            #pragma unroll
            for (int i = 0; i < 16; ++i) S[i] = 0.f;
            __builtin_amdgcn_s_setprio(1);
            S = __builtin_amdgcn_mfma_f32_32x32x16_bf16(kBh, qAh1, S, 0, 0, 0);
            S = __builtin_amdgcn_mfma_f32_32x32x16_bf16(kBl, qAh1, S, 0, 0, 0);
            S = __builtin_amdgcn_mfma_f32_32x32x16_bf16(kBh, qAl1, S, 0, 0, 0);
            __builtin_amdgcn_s_setprio(0);
            bf16x8 pA0, pA1;
            softmax_frags(S, pA0, pA1);
            __builtin_amdgcn_s_setprio(1);
            Cacc1 = __builtin_amdgcn_mfma_f32_32x32x16_bf16(pA0, vB0, Cacc1, 0, 0, 0);
            Cacc1 = __builtin_amdgcn_mfma_f32_32x32x16_bf16(pA1, vB1, Cacc1, 0, 0, 0);
            __builtin_amdgcn_s_setprio(0);
        }
    }

    // publish partials: D[m=qrow][n=d]; cols 0-15 = ctx(d), col 16 = l
    #pragma unroll
    for (int r = 0; r < 16; ++r) {
        const int row = (r & 3) + 8*(r >> 2) + 4*half;
        if (l31 < 16) {
            Cbuf[ks][row][h*HD + l31]      = Cacc0[r];
            Cbuf[ks][32 + row][h*HD + l31] = Cacc1[r];
        } else if (l31 == 16) {
            Lbuf[ks][h][row]      = Cacc0[r];
            Lbuf[ks][h][32 + row] = Cacc1[r];
        }
    }
    __syncthreads();

    // ---- MFMA epilogue: out[64 x 64] = (ctx * linv) @ Wproj + bproj ----
    // 4 waves: ct = wid&1 (col tile), rt = wid>>1 (row tile)
    if (wid < 4) {
        const int ct = wid & 1, rt = wid >> 1;
        const int t  = rt*32 + l31;          // qrow (A m-index)
        const int c  = ct*32 + l31;          // out col (B/D n-index)
        f32x16 D;
        const float bp = bproj[c];
        #pragma unroll
        for (int i = 0; i < 16; ++i) D[i] = bp;

        #pragma unroll
        for (int stp = 0; stp < 4; ++stp) {
            const float linv = 1.0f / (Lbuf[0][stp][t] + Lbuf[1][stp][t]);
            const int ib = stp*16 + half*8;
            const float4 x0 = *(const float4*)&Cbuf[0][t][ib];
            const float4 x1 = *(const float4*)&Cbuf[0][t][ib+4];
            const float4 y0 = *(const float4*)&Cbuf[1][t][ib];
            const float4 y1 = *(const float4*)&Cbuf[1][t][ib+4];
            float cv[8];
            cv[0] = (x0.x+y0.x)*linv; cv[1] = (x0.y+y0.y)*linv;
            cv[2] = (x0.z+y0.z)*linv; cv[3] = (x0.w+y0.w)*linv;
            cv[4] = (x1.x+y1.x)*linv; cv[5] = (x1.y+y1.y)*linv;
            cv[6] = (x1.z+y1.z)*linv; cv[7] = (x1.w+y1.w)*linv;
            u32x4 Ahv, Alv;
            #pragma unroll
            for (int jj = 0; jj < 4; ++jj) {
                const unsigned hw = pkbf(cv[2*jj], cv[2*jj+1]);
                const float h0 = bf2f((short)(hw & 0xffff));
                const float h1 = bf2f((short)(hw >> 16));
                Ahv[jj] = hw;
                Alv[jj] = pkbf(cv[2*jj] - h0, cv[2*jj+1] - h1);
            }
            const bf16x8 Ah = __builtin_bit_cast(bf16x8, Ahv);
            const bf16x8 Al = __builtin_bit_cast(bf16x8, Alv);
            const bf16x8 Bh = __builtin_bit_cast(bf16x8, Wl[ct][stp][0][lane]);
            const bf16x8 Bl = __builtin_bit_cast(bf16x8, Wl[ct][stp][1][lane]);
            D = __builtin_amdgcn_mfma_f32_32x32x16_bf16(Ah, Bh, D, 0, 0, 0);
            D = __builtin_amdgcn_mfma_f32_32x32x16_bf16(Ah, Bl, D, 0, 0, 0);
            D = __builtin_amdgcn_mfma_f32_32x32x16_bf16(Al, Bh, D, 0, 0, 0);
        }
        float* orow = out + ((size_t)b*TSEQ + qbase + rt*32)*DM + c;
        #pragma unroll
        for (int r = 0; r < 16; ++r) {
            const int tr = (r & 3) + 8*(r >> 2) + 4*half;
            orow[(size_t)tr * DM] = D[r];
        }
    }
}

extern "C" void kernel_launch(void* const* d_in, const int* in_sizes, int n_in,
                              void* d_out, int out_size, void* d_ws, size_t ws_size,
                              hipStream_t stream) {
    const float* x     = (const float*)d_in[0];
    const float* enc   = (const float*)d_in[1];
    const int*   mask  = (const int*)  d_in[2];
    const float* Wkv   = (const float*)d_in[3];
    const float* bkv   = (const float*)d_in[4];
    const float* Wq    = (const float*)d_in[5];
    const float* bq    = (const float*)d_in[6];
    const float* Wproj = (const float*)d_in[7];
    const float* bproj = (const float*)d_in[8];
    float* out = (float*)d_out;

    // ws: qhi,qlo,khi,klo 2MB each + vtt tiled (32 d-rows) 4MB = 12MB
    const size_t SZ = (size_t)BATCH*NH*TSEQ*HD;
    short* qhi = (short*)d_ws;
    short* qlo = qhi + SZ;
    short* khi = qlo + SZ;
    short* klo = khi + SZ;
    short* vtt = klo + SZ;   // BATCH*NH*32768 shorts

    proj_kernel<<<dim3(64, 12), dim3(256), 0, stream>>>(
        x, enc, Wkv, bkv, Wq, bq, mask, qhi, qlo, khi, klo, vtt);
    attn_kernel<<<dim3(256), dim3(512), 0, stream>>>(
        qhi, qlo, khi, klo, vtt, Wproj, bproj, out);
}